// Round 7
// baseline (277.430 us; speedup 1.0000x reference)
//
#include <hip/hip_runtime.h>
#include <hip/hip_bf16.h>

typedef unsigned short u16;
typedef __attribute__((ext_vector_type(8))) short bf16x8;   // 8 bf16 = 4 VGPRs
typedef __attribute__((ext_vector_type(4))) float f32x4;
typedef __attribute__((ext_vector_type(16))) float f32x16;

// ---------------- helpers ----------------

__device__ __forceinline__ u16 f2bf(float f) {
  union { float f; unsigned u; } v; v.f = f;
  unsigned r = v.u + 0x7fffu + ((v.u >> 16) & 1u);  // RNE
  return (u16)(r >> 16);
}

#if defined(__has_builtin)
#if __has_builtin(__builtin_amdgcn_cvt_pk_bf16_f32)
#define HAS_PK_BF16 1
#endif
#endif
__device__ __forceinline__ unsigned pk2bf(float a, float b) {
#ifdef HAS_PK_BF16
  typedef __attribute__((ext_vector_type(2))) __bf16 vbf2;
  union { vbf2 v; unsigned u; } u;
  u.v = __builtin_amdgcn_cvt_pk_bf16_f32(a, b);
  return u.u;
#else
  return (unsigned)f2bf(a) | ((unsigned)f2bf(b) << 16);
#endif
}

__device__ __forceinline__ f32x4 mfma16(bf16x8 a, bf16x8 b, f32x4 c) {
  return __builtin_amdgcn_mfma_f32_16x16x32_bf16(a, b, c, 0, 0, 0);
}
__device__ __forceinline__ f32x16 mfma32(bf16x8 a, bf16x8 b, f32x16 c) {
  return __builtin_amdgcn_mfma_f32_32x32x16_bf16(a, b, c, 0, 0, 0);
}

// async global->LDS, 16B per lane. LDS dest = wave-uniform base + lane*16.
__device__ __forceinline__ void gl_lds16(const void* g, void* l) {
  __builtin_amdgcn_global_load_lds((__attribute__((address_space(1))) void*)g,
                                   (__attribute__((address_space(3))) void*)l,
                                   16, 0, 0);
}

// ---------------- prep: x cvt + both weight transposes (one launch) ----------------

__global__ void prep(const float* __restrict__ x, const float* __restrict__ wq,
                     const float* __restrict__ wp, u16* __restrict__ xb,
                     u16* __restrict__ oq, u16* __restrict__ op) {
  __shared__ u16 tile[64][65];
  const int b = blockIdx.x, t = threadIdx.x;
  if (b < 8192) {  // x: fp32 -> bf16, 4 elems/thread
    int i = (b * 256 + t) * 4;
    float4 v = *(const float4*)(x + i);
    ushort4 o;
    o.x = f2bf(v.x); o.y = f2bf(v.y); o.z = f2bf(v.z); o.w = f2bf(v.w);
    *(ushort4*)(xb + i) = o;
    return;
  }
  // weight transpose: out[c][r] = bf16(in[r][c])
  const int tb = b - 8192;           // 0..1023
  const int bx = tb & 63, by = tb >> 6;
  const float* in; u16* out; int C, c0;
  if (bx < 48) { in = wq; out = oq; C = 3072; c0 = bx * 64; }
  else         { in = wp; out = op; C = 1024; c0 = (bx - 48) * 64; }
  const int R = 1024, r0 = by * 64;
  const int lc = t & 63, lr = t >> 6;
#pragma unroll
  for (int i = 0; i < 16; ++i) {
    int r = lr + i * 4;
    tile[r][lc] = f2bf(in[(size_t)(r0 + r) * C + c0 + lc]);
  }
  __syncthreads();
#pragma unroll
  for (int i = 0; i < 16; ++i) {
    int c = lr + i * 4;
    out[(size_t)(c0 + c) * R + r0 + lc] = tile[lc][c];
  }
}

// ---------------- 128x256 pipelined GEMM core (BK=64, 8 waves, 96 KB LDS) ----------------
// 1D grid + bijective XCD-chunked swizzle: xcd = bid&7 owns row-slab
// [8*xcd, 8*xcd+8) x all col-strips -> its 2 MB A-slab stays L2-resident across
// every col visit (A is the dominant re-read term). bx = (bid&7)*8 + ((bid>>3)&7),
// by = bid>>6. Bijective for nwg % 64 == 0 (qkv 768, proj 256).
// Counted-vmcnt schedule unchanged from round 6 (4 phases, 2 raw s_barriers,
// never vmcnt(0) mid-loop; A staged in 2 interleaved-row groups).

struct Smem128 { u16 A0[8192]; u16 B0[16384]; u16 A1[8192]; u16 B1[16384]; };

#define LDB128(base, off) (*(const bf16x8*)((const char*)(base) + (off)))
#define ISSUE_A(dst, j, k0) \
  gl_lds16(pA + (size_t)(j) * 32768 + (k0), (dst) + (j) * 4096 + dsel)
#define ISSUE_B(dst, j, k0) \
  gl_lds16(pB + (size_t)(j) * 65536 + (k0), (dst) + (j) * 4096 + dsel)

#define KSTEP(CA, CB, NA, NB, k0n, PF)                                         \
  do {                                                                         \
    bf16x8 aL[2][2], aH[2][2], bL[2][2], bH[2][2];                             \
    /* P1: read A-lo (region0) + B-lo; issue B0,B1; MFMA mtLo x ntLo */        \
    _Pragma("unroll") for (int mt = 0; mt < 2; ++mt) {                         \
      aL[mt][0] = LDB128(CA, aoff + mt * 2048 + cp0);                          \
      aL[mt][1] = LDB128(CA, aoff + mt * 2048 + cp1);                          \
    }                                                                          \
    _Pragma("unroll") for (int nt = 0; nt < 2; ++nt) {                         \
      bL[nt][0] = LDB128(CB, boff + nt * 2048 + cp0);                          \
      bL[nt][1] = LDB128(CB, boff + nt * 2048 + cp1);                          \
    }                                                                          \
    if (PF) { ISSUE_B(NB, 0, k0n); ISSUE_B(NB, 1, k0n); }                      \
    __builtin_amdgcn_s_setprio(1);                                             \
    _Pragma("unroll") for (int mt = 0; mt < 2; ++mt)                           \
      _Pragma("unroll") for (int nt = 0; nt < 2; ++nt) {                       \
        acc[mt][nt] = mfma16(aL[mt][0], bL[nt][0], acc[mt][nt]);               \
        acc[mt][nt] = mfma16(aL[mt][1], bL[nt][1], acc[mt][nt]);               \
      }                                                                        \
    __builtin_amdgcn_s_setprio(0);                                             \
    /* P2: read B-hi; issue B2,B3; MFMA mtLo x ntHi */                         \
    _Pragma("unroll") for (int nt = 0; nt < 2; ++nt) {                         \
      bH[nt][0] = LDB128(CB, boff + (nt + 2) * 2048 + cp0);                    \
      bH[nt][1] = LDB128(CB, boff + (nt + 2) * 2048 + cp1);                    \
    }                                                                          \
    if (PF) { ISSUE_B(NB, 2, k0n); ISSUE_B(NB, 3, k0n); }                      \
    __builtin_amdgcn_s_setprio(1);                                             \
    _Pragma("unroll") for (int mt = 0; mt < 2; ++mt)                           \
      _Pragma("unroll") for (int nt = 0; nt < 2; ++nt) {                       \
        acc[mt][nt + 2] = mfma16(aL[mt][0], bH[nt][0], acc[mt][nt + 2]);       \
        acc[mt][nt + 2] = mfma16(aL[mt][1], bH[nt][1], acc[mt][nt + 2]);       \
      }                                                                        \
    __builtin_amdgcn_s_setprio(0);                                             \
    /* P3: retire carry (prev A1), barrier, read A-hi (region1), issue A0 */   \
    if (PF) asm volatile("s_waitcnt vmcnt(4)" ::: "memory");                   \
    else    asm volatile("s_waitcnt vmcnt(0)" ::: "memory");                   \
    __builtin_amdgcn_s_barrier();                                              \
    _Pragma("unroll") for (int mt = 0; mt < 2; ++mt) {                         \
      aH[mt][0] = LDB128(CA, 8192 + aoff + mt * 2048 + cp0);                   \
      aH[mt][1] = LDB128(CA, 8192 + aoff + mt * 2048 + cp1);                   \
    }                                                                          \
    if (PF) ISSUE_A(NA, 0, k0n);                                               \
    __builtin_amdgcn_s_setprio(1);                                             \
    _Pragma("unroll") for (int mt = 0; mt < 2; ++mt)                           \
      _Pragma("unroll") for (int nt = 0; nt < 2; ++nt) {                       \
        acc[mt + 2][nt + 2] = mfma16(aH[mt][0], bH[nt][0], acc[mt + 2][nt + 2]); \
        acc[mt + 2][nt + 2] = mfma16(aH[mt][1], bH[nt][1], acc[mt + 2][nt + 2]); \
      }                                                                        \
    __builtin_amdgcn_s_setprio(0);                                             \
    /* P4: issue A1; MFMA mtHi x ntLo; boundary wait vmcnt(1) */               \
    if (PF) ISSUE_A(NA, 1, k0n);                                               \
    __builtin_amdgcn_s_setprio(1);                                             \
    _Pragma("unroll") for (int mt = 0; mt < 2; ++mt)                           \
      _Pragma("unroll") for (int nt = 0; nt < 2; ++nt) {                       \
        acc[mt + 2][nt] = mfma16(aH[mt][0], bL[nt][0], acc[mt + 2][nt]);       \
        acc[mt + 2][nt] = mfma16(aH[mt][1], bL[nt][1], acc[mt + 2][nt]);       \
      }                                                                        \
    __builtin_amdgcn_s_setprio(0);                                             \
    if (PF) asm volatile("s_waitcnt vmcnt(1)" ::: "memory");                   \
    __builtin_amdgcn_s_barrier();                                              \
  } while (0)

#define GEMM128_SETUP(Amat, Bmat)                                              \
  __shared__ Smem128 sm;                                                       \
  const int t = threadIdx.x, lane = t & 63, wave = t >> 6;                     \
  const int quad = lane >> 4, l15 = lane & 15;                                 \
  const int wm = wave >> 2, wn = wave & 3;                                     \
  const int bid = blockIdx.x;                                                  \
  const int bx = (bid & 7) * 8 + ((bid >> 3) & 7);  /* XCD-chunked swizzle */  \
  const int row0 = bx * 128, col0 = (bid >> 6) * 256;                          \
  const int g = t >> 3, f0 = g + (g & 32);   /* A rows {0-31,64-95} first */   \
  const int swz = (t & 7) ^ (g & 7);                                           \
  const u16* pA = (Amat) + (size_t)(row0 + f0) * 1024 + swz * 8;               \
  const u16* pB = (Bmat) + (size_t)(col0 + g) * 1024 + swz * 8;                \
  const size_t dsel = (size_t)wave * 512;                                      \
  const int rm = l15 & 7;                                                      \
  const int aoff = wm * 4096 + l15 * 128;                                      \
  const int boff = (wn * 64 + l15) * 128;                                      \
  const int cp0 = (quad ^ rm) << 4, cp1 = ((quad + 4) ^ rm) << 4;              \
  f32x4 acc[4][4] = {};                                                        \
  ISSUE_B(sm.B0, 0, 0); ISSUE_B(sm.B0, 1, 0);                                  \
  ISSUE_B(sm.B0, 2, 0); ISSUE_B(sm.B0, 3, 0);                                  \
  ISSUE_A(sm.A0, 0, 0); ISSUE_A(sm.A0, 1, 0);                                  \
  asm volatile("s_waitcnt vmcnt(1)" ::: "memory");                             \
  __builtin_amdgcn_s_barrier();                                                \
  _Pragma("unroll 1")                                                          \
  for (int kk = 0; kk < 8; ++kk) {                                             \
    KSTEP(sm.A0, sm.B0, sm.A1, sm.B1, (2 * kk + 1) * 64, 1);                   \
    KSTEP(sm.A1, sm.B1, sm.A0, sm.B0, (2 * kk + 2) * 64, (kk < 7));            \
  }

// ---------------- GEMM 1: qkv = x @ w_qkv + b_qkv ----------------
// Q pre-scaled by SCALE*log2(e). V blocks transpose per-wave through LDS
// (wave's 64 cols = exactly one head) and store Vt[bh][d][s] coalesced.

__global__ __launch_bounds__(512, 2) void gemm_qkv(
    const u16* __restrict__ A, const u16* __restrict__ Bt,
    const float* __restrict__ bias,
    u16* __restrict__ Qb, u16* __restrict__ Kb, u16* __restrict__ Vt) {
  GEMM128_SETUP(A, Bt)

  const int which = col0 >> 10;  // 0=Q 1=K 2=V (block-uniform)

  if (which == 2) {
    // per-wave transpose region (8 KB): [64 d][16 slots of 4 s], slot^=((d&7)<<1)
    u16* Ts = ((u16*)&sm) + wave * 4096;
#pragma unroll
    for (int nt = 0; nt < 4; ++nt) {
      const int d = nt * 16 + l15;
      const float bv = bias[col0 + wn * 64 + nt * 16 + l15];
#pragma unroll
      for (int mt = 0; mt < 4; ++mt) {
        uint2 pk;
        pk.x = pk2bf(acc[mt][nt][0] + bv, acc[mt][nt][1] + bv);
        pk.y = pk2bf(acc[mt][nt][2] + bv, acc[mt][nt][3] + bv);
        *(uint2*)((char*)Ts + d * 128 +
                  (((mt * 4 + quad) ^ ((d & 7) << 1)) << 3)) = pk;
      }
    }
    // same-wave LDS write->read: program order, no barrier needed
    const int h = ((col0 - 2048) >> 6) + wn;
    const int b_ = row0 >> 11;
    const int s0w = (row0 & 2047) + wm * 64;
    u16* vt = Vt + (size_t)(b_ * 16 + h) * 64 * 2048;
#pragma unroll
    for (int i = 0; i < 8; ++i) {
      const int d = i * 8 + (lane >> 3), c = lane & 7;
      uint4 v = *(const uint4*)((const char*)Ts + d * 128 + ((c ^ (d & 7)) << 4));
      *(uint4*)(vt + (size_t)d * 2048 + s0w + c * 8) = v;
    }
    return;
  }

  u16* dst = which == 0 ? Qb : Kb;
  const float qscale = which == 0 ? 0.1803368801111137f : 1.0f;  // 0.125*log2(e)
#pragma unroll
  for (int nt = 0; nt < 4; ++nt) {
    const int col = (col0 & 1023) + wn * 64 + nt * 16 + l15;
    const float bv = bias[col0 + wn * 64 + nt * 16 + l15];
    const int h = col >> 6, d = col & 63;
#pragma unroll
    for (int mt = 0; mt < 4; ++mt) {
#pragma unroll
      for (int r = 0; r < 4; ++r) {
        const int row = row0 + wm * 64 + mt * 16 + quad * 4 + r;  // b*2048+s
        const int bb = row >> 11, s = row & 2047;
        dst[(((size_t)bb * 16 + h) * 2048 + s) * 64 + d] =
            f2bf((acc[mt][nt][r] + bv) * qscale);
      }
    }
  }
}

// ---------------- GEMM 2: out = attn_out @ w_proj + b_proj (fp32 out) ----------------

__global__ __launch_bounds__(512, 2) void gemm_proj(
    const u16* __restrict__ A, const u16* __restrict__ Bt,
    const float* __restrict__ bias, float* __restrict__ C) {
  GEMM128_SETUP(A, Bt)

#pragma unroll
  for (int nt = 0; nt < 4; ++nt) {
    const int col = col0 + wn * 64 + nt * 16 + l15;
    const float bv = bias[col];
#pragma unroll
    for (int mt = 0; mt < 4; ++mt) {
#pragma unroll
      for (int r = 0; r < 4; ++r) {
        const int row = row0 + wm * 64 + mt * 16 + quad * 4 + r;
        C[(size_t)row * 1024 + col] = acc[mt][nt][r] + bv;
      }
    }
  }
}

// ---------------- Flash attention v6: interleaved key-halves for intra-wave ILP ----
// v5 structure kept (64 q/wave, shared K/V frags, in-register softmax). v6: the two
// independent key-halves (kh=0,1) are computed TOGETHER -- QK x4 chains, then SM x4,
// then PV -- doubling the independent MFMA/VALU chains the scheduler can interleave
// (the 2-wave/SIMD occupancy is grid-capped, so the extra ~50 VGPR are free).
// Softmax call order and acc update order are IDENTICAL to v5 -> bit-identical output.

__device__ __forceinline__ void softmax32(const f32x16& s, float& l,
                                          bf16x8& paA, bf16x8& paB) {
  unsigned D[8];
#pragma unroll
  for (int i = 0; i < 8; ++i) {
    float a = __builtin_amdgcn_exp2f(s[2 * i]);
    float b = __builtin_amdgcn_exp2f(s[2 * i + 1]);
    l += a + b;
    D[i] = pk2bf(a, b);
  }
  {
    unsigned x = D[0], x2 = D[1], y = D[2], y2 = D[3];
    asm volatile("v_permlane32_swap_b32 %0, %1" : "+v"(x), "+v"(y));
    asm volatile("v_permlane32_swap_b32 %0, %1" : "+v"(x2), "+v"(y2));
    union { unsigned u[4]; bf16x8 v; } p;
    p.u[0] = x; p.u[1] = x2; p.u[2] = y; p.u[3] = y2;
    paA = p.v;
  }
  {
    unsigned x = D[4], x2 = D[5], y = D[6], y2 = D[7];
    asm volatile("v_permlane32_swap_b32 %0, %1" : "+v"(x), "+v"(y));
    asm volatile("v_permlane32_swap_b32 %0, %1" : "+v"(x2), "+v"(y2));
    union { unsigned u[4]; bf16x8 v; } p;
    p.u[0] = x; p.u[1] = x2; p.u[2] = y; p.u[3] = y2;
    paB = p.v;
  }
}

__global__ __launch_bounds__(256, 2) void attn_kernel(
    const u16* __restrict__ Qb, const u16* __restrict__ Kb,
    const u16* __restrict__ Vt, u16* __restrict__ Ob) {
  __shared__ u16 KsA[64 * 64], KsB[64 * 64];  // 8 KB each, swizzled [key][d-chunk]
  __shared__ u16 VsA[64 * 64], VsB[64 * 64];  // 8 KB each, swizzled [d][key-chunk]
  const int bh = blockIdx.x, q0 = blockIdx.y * 256;
  const u16* Qp = Qb + (size_t)bh * 2048 * 64;
  const u16* Kp = Kb + (size_t)bh * 2048 * 64;
  const u16* Vp = Vt + (size_t)bh * 64 * 2048;
  const int t = threadIdx.x, lane = t & 63, wave = t >> 6;
  const int l31 = lane & 31, hi = lane >> 5;

  const int kr0 = t >> 3, kc0 = (t & 7) ^ (kr0 & 7);
  const int kr1 = (256 + t) >> 3, kc1 = ((256 + t) & 7) ^ (kr1 & 7);
  const u16* Kg0 = Kp + (size_t)kr0 * 64 + kc0 * 8;
  const u16* Kg1 = Kp + (size_t)kr1 * 64 + kc1 * 8;
  const u16* Vg0 = Vp + (size_t)kr0 * 2048 + kc0 * 8;
  const u16* Vg1 = Vp + (size_t)kr1 * 2048 + kc1 * 8;
  const size_t dof0 = (size_t)wave * 512;
  const size_t dof1 = 2048 + (size_t)wave * 512;

#define STAGE(Kd, Vd, key0)                                   \
  do {                                                        \
    gl_lds16(Kg0 + (size_t)(key0) * 64, (Kd) + dof0);         \
    gl_lds16(Kg1 + (size_t)(key0) * 64, (Kd) + dof1);         \
    gl_lds16(Vg0 + (key0), (Vd) + dof0);                      \
    gl_lds16(Vg1 + (key0), (Vd) + dof1);                      \
  } while (0)

  STAGE(KsA, VsA, 0);
  const u16* Qr0 = Qp + (size_t)(q0 + wave * 64 + l31) * 64 + hi * 8;
  const u16* Qr1 = Qr0 + 32 * 64;
  bf16x8 qf0[4], qf1[4];
#pragma unroll
  for (int dc = 0; dc < 4; ++dc) {
    qf0[dc] = *(const bf16x8*)(Qr0 + dc * 16);
    qf1[dc] = *(const bf16x8*)(Qr1 + dc * 16);
  }
  __syncthreads();

  const int rm = l31 & 7;
  int off[2][4];
#pragma unroll
  for (int x = 0; x < 2; ++x)
#pragma unroll
    for (int c = 0; c < 4; ++c)
      off[x][c] = x * 4096 + l31 * 128 + (((c * 2 + hi) ^ rm) << 4);

  f32x16 acc00 = {}, acc01 = {}, acc10 = {}, acc11 = {};  // [qb][d-half]
  float l0 = 0.f, l1 = 0.f;

#define TILE(Ks, Vs)                                                          \
  do {                                                                        \
    f32x16 s00 = {}, s01 = {}, s10 = {}, s11 = {};  /* [kh][qb] */            \
    __builtin_amdgcn_s_setprio(1);                                            \
    _Pragma("unroll")                                                         \
    for (int dc = 0; dc < 4; ++dc) {                                          \
      bf16x8 kf0 = *(const bf16x8*)((const char*)(Ks) + off[0][dc]);          \
      bf16x8 kf1 = *(const bf16x8*)((const char*)(Ks) + off[1][dc]);          \
      s00 = mfma32(kf0, qf0[dc], s00);                                        \
      s01 = mfma32(kf0, qf1[dc], s01);                                        \
      s10 = mfma32(kf1, qf0[dc], s10);                                        \
      s11 = mfma32(kf1, qf1[dc], s11);                                        \
    }                                                                         \
    __builtin_amdgcn_s_setprio(0);                                            \
    bf16x8 pa[2][2][2]; /* [kh][qb][chunk] */                                 \
    softmax32(s00, l0, pa[0][0][0], pa[0][0][1]);                             \
    softmax32(s01, l1, pa[0][1][0], pa[0][1][1]);                             \
    softmax32(s10, l0, pa[1][0][0], pa[1][0][1]);                             \
    softmax32(s11, l1, pa[1][1][0], pa[1][1][1]);                             \
    __builtin_amdgcn_s_setprio(1);                                            \
    _Pragma("unroll")                                                         \
    for (int kh = 0; kh < 2; ++kh)                                            \
      _Pragma("unroll")                                                       \
      for (int ci = 0; ci < 2; ++ci) {                                        \
        const int c = 2 * kh + ci;                                            \
        bf16x8 vlo = *(const bf16x8*)((const char*)(Vs) + off[0][c]);         \
        bf16x8 vhi2 = *(const bf16x8*)((const char*)(Vs) + off[1][c]);        \
        acc00 = mfma32(pa[kh][0][ci], vlo, acc00);                            \
        acc01 = mfma32(pa[kh][0][ci], vhi2, acc01);                           \
        acc10 = mfma32(pa[kh][1][ci], vlo, acc10);                            \
        acc11 = mfma32(pa[kh][1][ci], vhi2, acc11);                           \
      }                                                                       \
    __builtin_amdgcn_s_setprio(0);                                            \
  } while (0)

#pragma unroll 1
  for (int kt2 = 0; kt2 < 16; ++kt2) {
    const int kt = kt2 * 2;
    STAGE(KsB, VsB, (kt + 1) * 64);
    TILE(KsA, VsA);
    __syncthreads();
    if (kt2 < 15) STAGE(KsA, VsA, (kt + 2) * 64);
    TILE(KsB, VsB);
    __syncthreads();
  }
#undef TILE
#undef STAGE

  l0 += __shfl_xor(l0, 32);
  l1 += __shfl_xor(l1, 32);
  float inv0 = 1.f / l0, inv1 = 1.f / l1;

  const int b_ = bh >> 4, h = bh & 15;
  const int qw = q0 + wave * 64;
#pragma unroll
  for (int r = 0; r < 16; ++r) {
    const int ql = (r & 3) + 8 * (r >> 2) + 4 * hi;
    float iv0 = __shfl(inv0, ql);
    float iv1 = __shfl(inv1, ql);
    size_t base0 = ((size_t)b_ * 2048 + qw + ql) * 1024 + h * 64;
    size_t base1 = base0 + (size_t)32 * 1024;
    Ob[base0 + l31] = f2bf(acc00[r] * iv0);
    Ob[base0 + 32 + l31] = f2bf(acc01[r] * iv0);
    Ob[base1 + l31] = f2bf(acc10[r] * iv1);
    Ob[base1 + 32 + l31] = f2bf(acc11[r] * iv1);
  }
}

// ---------------- launch ----------------

extern "C" void kernel_launch(void* const* d_in, const int* in_sizes, int n_in,
                              void* d_out, int out_size, void* d_ws, size_t ws_size,
                              hipStream_t stream) {
  const float* x      = (const float*)d_in[0];
  const float* w_qkv  = (const float*)d_in[1];
  const float* b_qkv  = (const float*)d_in[2];
  const float* w_proj = (const float*)d_in[3];
  const float* b_proj = (const float*)d_in[4];
  float* out = (float*)d_out;
  char* ws = (char*)d_ws;

  // workspace layout (bytes)
  u16* xb    = (u16*)(ws);                 // 16 MB  [8192][1024]; later reused as attn_out
  u16* wqkvt = (u16*)(ws + 16777216);      //  6 MB  [3072][1024]
  u16* wprjt = (u16*)(ws + 23068672);      //  2 MB  [1024][1024]
  u16* Qb    = (u16*)(ws + 25165824);      // 16 MB  [64][2048][64]
  u16* Kb    = (u16*)(ws + 41943040);      // 16 MB
  u16* Vt    = (u16*)(ws + 58720256);      // 16 MB  [64][64][2048]  (direct from gemm_qkv)
  u16* Ob    = xb;                         // alias: x consumed by gemm_qkv before attn writes
  if (ws_size < 92274688u) return;  // insufficient scratch -> visible failure

  prep<<<9216, 256, 0, stream>>>(x, w_qkv, w_proj, xb, wqkvt, wprjt);
  gemm_qkv<<<768, 512, 0, stream>>>(xb, wqkvt, b_qkv, Qb, Kb, Vt);
  attn_kernel<<<dim3(64, 8), 256, 0, stream>>>(Qb, Kb, Vt, Ob);
  gemm_proj<<<256, 512, 0, stream>>>(Ob, wprjt, b_proj, out);
}

// Round 8
// 253.353 us; speedup vs baseline: 1.0950x; 1.0950x over previous
//
#include <hip/hip_runtime.h>
#include <hip/hip_bf16.h>

typedef unsigned short u16;
typedef __attribute__((ext_vector_type(8))) short bf16x8;   // 8 bf16 = 4 VGPRs
typedef __attribute__((ext_vector_type(4))) float f32x4;
typedef __attribute__((ext_vector_type(16))) float f32x16;

// ---------------- helpers ----------------

__device__ __forceinline__ u16 f2bf(float f) {
  union { float f; unsigned u; } v; v.f = f;
  unsigned r = v.u + 0x7fffu + ((v.u >> 16) & 1u);  // RNE
  return (u16)(r >> 16);
}

#if defined(__has_builtin)
#if __has_builtin(__builtin_amdgcn_cvt_pk_bf16_f32)
#define HAS_PK_BF16 1
#endif
#endif
__device__ __forceinline__ unsigned pk2bf(float a, float b) {
#ifdef HAS_PK_BF16
  typedef __attribute__((ext_vector_type(2))) __bf16 vbf2;
  union { vbf2 v; unsigned u; } u;
  u.v = __builtin_amdgcn_cvt_pk_bf16_f32(a, b);
  return u.u;
#else
  return (unsigned)f2bf(a) | ((unsigned)f2bf(b) << 16);
#endif
}

__device__ __forceinline__ f32x4 mfma16(bf16x8 a, bf16x8 b, f32x4 c) {
  return __builtin_amdgcn_mfma_f32_16x16x32_bf16(a, b, c, 0, 0, 0);
}
__device__ __forceinline__ f32x16 mfma32(bf16x8 a, bf16x8 b, f32x16 c) {
  return __builtin_amdgcn_mfma_f32_32x32x16_bf16(a, b, c, 0, 0, 0);
}

// async global->LDS, 16B per lane. LDS dest = wave-uniform base + lane*16.
__device__ __forceinline__ void gl_lds16(const void* g, void* l) {
  __builtin_amdgcn_global_load_lds((__attribute__((address_space(1))) void*)g,
                                   (__attribute__((address_space(3))) void*)l,
                                   16, 0, 0);
}

// ---------------- conversion kernels ----------------

__global__ void cvt_f32_bf16(const float* __restrict__ in, u16* __restrict__ out, int n) {
  int i = (blockIdx.x * blockDim.x + threadIdx.x) * 4;
  if (i >= n) return;
  float4 v = *(const float4*)(in + i);
  u16 o0 = f2bf(v.x), o1 = f2bf(v.y), o2 = f2bf(v.z), o3 = f2bf(v.w);
  ushort4 o; o.x = o0; o.y = o1; o.z = o2; o.w = o3;
  *(ushort4*)(out + i) = o;
}

// merged weight transposes: bx<48 -> w_qkv [1024][3072], else w_proj [1024][1024]
__global__ void transpose_cvt2(const float* __restrict__ wq, const float* __restrict__ wp,
                               u16* __restrict__ oq, u16* __restrict__ op) {
  __shared__ u16 tile[64][65];
  const int bx = blockIdx.x;
  const float* in; u16* out; int C, c0;
  if (bx < 48) { in = wq; out = oq; C = 3072; c0 = bx * 64; }
  else         { in = wp; out = op; C = 1024; c0 = (bx - 48) * 64; }
  const int R = 1024;
  int r0 = blockIdx.y * 64;
  int lc = threadIdx.x & 63, lr = threadIdx.x >> 6;
#pragma unroll
  for (int i = 0; i < 16; ++i) {
    int r = lr + i * 4;
    tile[r][lc] = f2bf(in[(size_t)(r0 + r) * C + c0 + lc]);
  }
  __syncthreads();
#pragma unroll
  for (int i = 0; i < 16; ++i) {
    int c = lr + i * 4;
    out[(size_t)(c0 + c) * R + r0 + lc] = tile[lc][c];
  }
}

// ---------------- 128x256 pipelined GEMM core (BK=64, 8 waves, 96 KB LDS) ----------------
// Round-6 structure (best measured) with ONE change: earlier prefetch issue.
// v8 issue order per step: P1 {B0,B1} | P2 {B2,B3,A0} | P3 {A1} | P4 {}.
// A0-next now has P3+P4 (~300cy) of latency coverage before the end-of-step
// vmcnt(1) (was P4-only ~150cy); A1-next has a FULL step (needed at next-P3).
// FIFO: P3 wait vmcnt(5) retires A1-cur (outstanding there = A1-cur + B0-3,A0-next);
// end-of-step vmcnt(1) retires B0-3+A0-next, leaves A1-next in flight.
// Never vmcnt(0) mid-loop. Buffer load/store sequence unchanged -> bit-identical.

struct Smem128 { u16 A0[8192]; u16 B0[16384]; u16 A1[8192]; u16 B1[16384]; };

#define LDB128(base, off) (*(const bf16x8*)((const char*)(base) + (off)))
#define ISSUE_A(dst, j, k0) \
  gl_lds16(pA + (size_t)(j) * 32768 + (k0), (dst) + (j) * 4096 + dsel)
#define ISSUE_B(dst, j, k0) \
  gl_lds16(pB + (size_t)(j) * 65536 + (k0), (dst) + (j) * 4096 + dsel)

#define KSTEP(CA, CB, NA, NB, k0n, PF)                                         \
  do {                                                                         \
    bf16x8 aL[2][2], aH[2][2], bL[2][2], bH[2][2];                             \
    /* P1: read A-lo (region0) + B-lo; issue B0,B1; MFMA mtLo x ntLo */        \
    _Pragma("unroll") for (int mt = 0; mt < 2; ++mt) {                         \
      aL[mt][0] = LDB128(CA, aoff + mt * 2048 + cp0);                          \
      aL[mt][1] = LDB128(CA, aoff + mt * 2048 + cp1);                          \
    }                                                                          \
    _Pragma("unroll") for (int nt = 0; nt < 2; ++nt) {                         \
      bL[nt][0] = LDB128(CB, boff + nt * 2048 + cp0);                          \
      bL[nt][1] = LDB128(CB, boff + nt * 2048 + cp1);                          \
    }                                                                          \
    if (PF) { ISSUE_B(NB, 0, k0n); ISSUE_B(NB, 1, k0n); }                      \
    __builtin_amdgcn_s_setprio(1);                                             \
    _Pragma("unroll") for (int mt = 0; mt < 2; ++mt)                           \
      _Pragma("unroll") for (int nt = 0; nt < 2; ++nt) {                       \
        acc[mt][nt] = mfma16(aL[mt][0], bL[nt][0], acc[mt][nt]);               \
        acc[mt][nt] = mfma16(aL[mt][1], bL[nt][1], acc[mt][nt]);               \
      }                                                                        \
    __builtin_amdgcn_s_setprio(0);                                             \
    /* P2: read B-hi; issue B2,B3,A0; MFMA mtLo x ntHi */                      \
    _Pragma("unroll") for (int nt = 0; nt < 2; ++nt) {                         \
      bH[nt][0] = LDB128(CB, boff + (nt + 2) * 2048 + cp0);                    \
      bH[nt][1] = LDB128(CB, boff + (nt + 2) * 2048 + cp1);                    \
    }                                                                          \
    if (PF) { ISSUE_B(NB, 2, k0n); ISSUE_B(NB, 3, k0n); ISSUE_A(NA, 0, k0n); } \
    __builtin_amdgcn_s_setprio(1);                                             \
    _Pragma("unroll") for (int mt = 0; mt < 2; ++mt)                           \
      _Pragma("unroll") for (int nt = 0; nt < 2; ++nt) {                       \
        acc[mt][nt + 2] = mfma16(aL[mt][0], bH[nt][0], acc[mt][nt + 2]);       \
        acc[mt][nt + 2] = mfma16(aL[mt][1], bH[nt][1], acc[mt][nt + 2]);       \
      }                                                                        \
    __builtin_amdgcn_s_setprio(0);                                             \
    /* P3: retire A1-cur (vmcnt(5): 6 outstanding), barrier, read A-hi, issue A1 */ \
    if (PF) asm volatile("s_waitcnt vmcnt(5)" ::: "memory");                   \
    else    asm volatile("s_waitcnt vmcnt(0)" ::: "memory");                   \
    __builtin_amdgcn_s_barrier();                                              \
    _Pragma("unroll") for (int mt = 0; mt < 2; ++mt) {                         \
      aH[mt][0] = LDB128(CA, 8192 + aoff + mt * 2048 + cp0);                   \
      aH[mt][1] = LDB128(CA, 8192 + aoff + mt * 2048 + cp1);                   \
    }                                                                          \
    if (PF) ISSUE_A(NA, 1, k0n);                                               \
    __builtin_amdgcn_s_setprio(1);                                             \
    _Pragma("unroll") for (int mt = 0; mt < 2; ++mt)                           \
      _Pragma("unroll") for (int nt = 0; nt < 2; ++nt) {                       \
        acc[mt + 2][nt + 2] = mfma16(aH[mt][0], bH[nt][0], acc[mt + 2][nt + 2]); \
        acc[mt + 2][nt + 2] = mfma16(aH[mt][1], bH[nt][1], acc[mt + 2][nt + 2]); \
      }                                                                        \
    __builtin_amdgcn_s_setprio(0);                                             \
    /* P4: MFMA mtHi x ntLo; boundary wait vmcnt(1) */                         \
    __builtin_amdgcn_s_setprio(1);                                             \
    _Pragma("unroll") for (int mt = 0; mt < 2; ++mt)                           \
      _Pragma("unroll") for (int nt = 0; nt < 2; ++nt) {                       \
        acc[mt + 2][nt] = mfma16(aH[mt][0], bL[nt][0], acc[mt + 2][nt]);       \
        acc[mt + 2][nt] = mfma16(aH[mt][1], bL[nt][1], acc[mt + 2][nt]);       \
      }                                                                        \
    __builtin_amdgcn_s_setprio(0);                                             \
    if (PF) asm volatile("s_waitcnt vmcnt(1)" ::: "memory");                   \
    __builtin_amdgcn_s_barrier();                                              \
  } while (0)

#define GEMM128_SETUP(Amat, Bmat)                                              \
  __shared__ Smem128 sm;                                                       \
  const int t = threadIdx.x, lane = t & 63, wave = t >> 6;                     \
  const int quad = lane >> 4, l15 = lane & 15;                                 \
  const int wm = wave >> 2, wn = wave & 3;                                     \
  const int row0 = blockIdx.x * 128, col0 = blockIdx.y * 256;                  \
  const int g = t >> 3, f0 = g + (g & 32);   /* A rows {0-31,64-95} first */   \
  const int swz = (t & 7) ^ (g & 7);                                           \
  const u16* pA = (Amat) + (size_t)(row0 + f0) * 1024 + swz * 8;               \
  const u16* pB = (Bmat) + (size_t)(col0 + g) * 1024 + swz * 8;                \
  const size_t dsel = (size_t)wave * 512;                                      \
  const int rm = l15 & 7;                                                      \
  const int aoff = wm * 4096 + l15 * 128;                                      \
  const int boff = (wn * 64 + l15) * 128;                                      \
  const int cp0 = (quad ^ rm) << 4, cp1 = ((quad + 4) ^ rm) << 4;              \
  f32x4 acc[4][4] = {};                                                        \
  ISSUE_B(sm.B0, 0, 0); ISSUE_B(sm.B0, 1, 0);                                  \
  ISSUE_B(sm.B0, 2, 0); ISSUE_B(sm.B0, 3, 0);                                  \
  ISSUE_A(sm.A0, 0, 0); ISSUE_A(sm.A0, 1, 0);                                  \
  asm volatile("s_waitcnt vmcnt(1)" ::: "memory");                             \
  __builtin_amdgcn_s_barrier();                                                \
  _Pragma("unroll 1")                                                          \
  for (int kk = 0; kk < 8; ++kk) {                                             \
    KSTEP(sm.A0, sm.B0, sm.A1, sm.B1, (2 * kk + 1) * 64, 1);                   \
    KSTEP(sm.A1, sm.B1, sm.A0, sm.B0, (2 * kk + 2) * 64, (kk < 7));            \
  }

// ---------------- GEMM 1: qkv = x @ w_qkv + b_qkv ----------------
// Q pre-scaled by SCALE*log2(e). V blocks transpose per-wave through LDS
// (wave's 64 cols = exactly one head) and store Vt[bh][d][s] coalesced.

__global__ __launch_bounds__(512, 2) void gemm_qkv(
    const u16* __restrict__ A, const u16* __restrict__ Bt,
    const float* __restrict__ bias,
    u16* __restrict__ Qb, u16* __restrict__ Kb, u16* __restrict__ Vt) {
  GEMM128_SETUP(A, Bt)

  const int which = col0 >> 10;  // 0=Q 1=K 2=V (block-uniform)

  if (which == 2) {
    // per-wave transpose region (8 KB): [64 d][16 slots of 4 s], slot^=((d&7)<<1)
    u16* Ts = ((u16*)&sm) + wave * 4096;
#pragma unroll
    for (int nt = 0; nt < 4; ++nt) {
      const int d = nt * 16 + l15;
      const float bv = bias[col0 + wn * 64 + nt * 16 + l15];
#pragma unroll
      for (int mt = 0; mt < 4; ++mt) {
        uint2 pk;
        pk.x = pk2bf(acc[mt][nt][0] + bv, acc[mt][nt][1] + bv);
        pk.y = pk2bf(acc[mt][nt][2] + bv, acc[mt][nt][3] + bv);
        *(uint2*)((char*)Ts + d * 128 +
                  (((mt * 4 + quad) ^ ((d & 7) << 1)) << 3)) = pk;
      }
    }
    // same-wave LDS write->read: program order, no barrier needed
    const int h = ((col0 - 2048) >> 6) + wn;
    const int b_ = row0 >> 11;
    const int s0w = (row0 & 2047) + wm * 64;
    u16* vt = Vt + (size_t)(b_ * 16 + h) * 64 * 2048;
#pragma unroll
    for (int i = 0; i < 8; ++i) {
      const int d = i * 8 + (lane >> 3), c = lane & 7;
      uint4 v = *(const uint4*)((const char*)Ts + d * 128 + ((c ^ (d & 7)) << 4));
      *(uint4*)(vt + (size_t)d * 2048 + s0w + c * 8) = v;
    }
    return;
  }

  u16* dst = which == 0 ? Qb : Kb;
  const float qscale = which == 0 ? 0.1803368801111137f : 1.0f;  // 0.125*log2(e)
#pragma unroll
  for (int nt = 0; nt < 4; ++nt) {
    const int col = (col0 & 1023) + wn * 64 + nt * 16 + l15;
    const float bv = bias[col0 + wn * 64 + nt * 16 + l15];
    const int h = col >> 6, d = col & 63;
#pragma unroll
    for (int mt = 0; mt < 4; ++mt) {
#pragma unroll
      for (int r = 0; r < 4; ++r) {
        const int row = row0 + wm * 64 + mt * 16 + quad * 4 + r;  // b*2048+s
        const int bb = row >> 11, s = row & 2047;
        dst[(((size_t)bb * 16 + h) * 2048 + s) * 64 + d] =
            f2bf((acc[mt][nt][r] + bv) * qscale);
      }
    }
  }
}

// ---------------- GEMM 2: out = attn_out @ w_proj + b_proj (fp32 out) ----------------

__global__ __launch_bounds__(512, 2) void gemm_proj(
    const u16* __restrict__ A, const u16* __restrict__ Bt,
    const float* __restrict__ bias, float* __restrict__ C) {
  GEMM128_SETUP(A, Bt)

#pragma unroll
  for (int nt = 0; nt < 4; ++nt) {
    const int col = col0 + wn * 64 + nt * 16 + l15;
    const float bv = bias[col];
#pragma unroll
    for (int mt = 0; mt < 4; ++mt) {
#pragma unroll
      for (int r = 0; r < 4; ++r) {
        const int row = row0 + wm * 64 + mt * 16 + quad * 4 + r;
        C[(size_t)row * 1024 + col] = acc[mt][nt][r] + bv;
      }
    }
  }
}

// ---------------- Flash attention v5: 64 q/wave, shared K/V frags ----------------
// (round-6 best: serial key-halves, in-register softmax, static dbuf, setprio)

__device__ __forceinline__ void softmax32(const f32x16& s, float& l,
                                          bf16x8& paA, bf16x8& paB) {
  unsigned D[8];
#pragma unroll
  for (int i = 0; i < 8; ++i) {
    float a = __builtin_amdgcn_exp2f(s[2 * i]);
    float b = __builtin_amdgcn_exp2f(s[2 * i + 1]);
    l += a + b;
    D[i] = pk2bf(a, b);
  }
  {
    unsigned x = D[0], x2 = D[1], y = D[2], y2 = D[3];
    asm volatile("v_permlane32_swap_b32 %0, %1" : "+v"(x), "+v"(y));
    asm volatile("v_permlane32_swap_b32 %0, %1" : "+v"(x2), "+v"(y2));
    union { unsigned u[4]; bf16x8 v; } p;
    p.u[0] = x; p.u[1] = x2; p.u[2] = y; p.u[3] = y2;
    paA = p.v;
  }
  {
    unsigned x = D[4], x2 = D[5], y = D[6], y2 = D[7];
    asm volatile("v_permlane32_swap_b32 %0, %1" : "+v"(x), "+v"(y));
    asm volatile("v_permlane32_swap_b32 %0, %1" : "+v"(x2), "+v"(y2));
    union { unsigned u[4]; bf16x8 v; } p;
    p.u[0] = x; p.u[1] = x2; p.u[2] = y; p.u[3] = y2;
    paB = p.v;
  }
}

__global__ __launch_bounds__(256, 2) void attn_kernel(
    const u16* __restrict__ Qb, const u16* __restrict__ Kb,
    const u16* __restrict__ Vt, u16* __restrict__ Ob) {
  __shared__ u16 KsA[64 * 64], KsB[64 * 64];  // 8 KB each, swizzled [key][d-chunk]
  __shared__ u16 VsA[64 * 64], VsB[64 * 64];  // 8 KB each, swizzled [d][key-chunk]
  const int bh = blockIdx.x, q0 = blockIdx.y * 256;
  const u16* Qp = Qb + (size_t)bh * 2048 * 64;
  const u16* Kp = Kb + (size_t)bh * 2048 * 64;
  const u16* Vp = Vt + (size_t)bh * 64 * 2048;
  const int t = threadIdx.x, lane = t & 63, wave = t >> 6;
  const int l31 = lane & 31, hi = lane >> 5;

  const int kr0 = t >> 3, kc0 = (t & 7) ^ (kr0 & 7);
  const int kr1 = (256 + t) >> 3, kc1 = ((256 + t) & 7) ^ (kr1 & 7);
  const u16* Kg0 = Kp + (size_t)kr0 * 64 + kc0 * 8;
  const u16* Kg1 = Kp + (size_t)kr1 * 64 + kc1 * 8;
  const u16* Vg0 = Vp + (size_t)kr0 * 2048 + kc0 * 8;
  const u16* Vg1 = Vp + (size_t)kr1 * 2048 + kc1 * 8;
  const size_t dof0 = (size_t)wave * 512;
  const size_t dof1 = 2048 + (size_t)wave * 512;

#define STAGE(Kd, Vd, key0)                                   \
  do {                                                        \
    gl_lds16(Kg0 + (size_t)(key0) * 64, (Kd) + dof0);         \
    gl_lds16(Kg1 + (size_t)(key0) * 64, (Kd) + dof1);         \
    gl_lds16(Vg0 + (key0), (Vd) + dof0);                      \
    gl_lds16(Vg1 + (key0), (Vd) + dof1);                      \
  } while (0)

  STAGE(KsA, VsA, 0);
  const u16* Qr0 = Qp + (size_t)(q0 + wave * 64 + l31) * 64 + hi * 8;
  const u16* Qr1 = Qr0 + 32 * 64;
  bf16x8 qf0[4], qf1[4];
#pragma unroll
  for (int dc = 0; dc < 4; ++dc) {
    qf0[dc] = *(const bf16x8*)(Qr0 + dc * 16);
    qf1[dc] = *(const bf16x8*)(Qr1 + dc * 16);
  }
  __syncthreads();

  const int rm = l31 & 7;
  int off[2][4];
#pragma unroll
  for (int x = 0; x < 2; ++x)
#pragma unroll
    for (int c = 0; c < 4; ++c)
      off[x][c] = x * 4096 + l31 * 128 + (((c * 2 + hi) ^ rm) << 4);

  f32x16 acc00 = {}, acc01 = {}, acc10 = {}, acc11 = {};  // [qb][d-half]
  float l0 = 0.f, l1 = 0.f;

#define TILE(Ks, Vs)                                                          \
  do {                                                                        \
    _Pragma("unroll")                                                         \
    for (int kh = 0; kh < 2; ++kh) {                                          \
      f32x16 s0 = {}, s1 = {};                                                \
      __builtin_amdgcn_s_setprio(1);                                          \
      _Pragma("unroll")                                                       \
      for (int dc = 0; dc < 4; ++dc) {                                        \
        bf16x8 kf = *(const bf16x8*)((const char*)(Ks) + off[kh][dc]);        \
        s0 = mfma32(kf, qf0[dc], s0);                                         \
        s1 = mfma32(kf, qf1[dc], s1);                                         \
      }                                                                       \
      __builtin_amdgcn_s_setprio(0);                                          \
      bf16x8 pa00, pa01, pa10, pa11;                                          \
      softmax32(s0, l0, pa00, pa01);                                          \
      softmax32(s1, l1, pa10, pa11);                                          \
      __builtin_amdgcn_s_setprio(1);                                          \
      _Pragma("unroll")                                                       \
      for (int ci = 0; ci < 2; ++ci) {                                        \
        const int c = 2 * kh + ci;                                            \
        bf16x8 vlo = *(const bf16x8*)((const char*)(Vs) + off[0][c]);         \
        bf16x8 vhiv = *(const bf16x8*)((const char*)(Vs) + off[1][c]);        \
        bf16x8 pa0 = ci ? pa01 : pa00;                                        \
        bf16x8 pa1 = ci ? pa11 : pa10;                                        \
        acc00 = mfma32(pa0, vlo, acc00);                                      \
        acc01 = mfma32(pa0, vhiv, acc01);                                     \
        acc10 = mfma32(pa1, vlo, acc10);                                      \
        acc11 = mfma32(pa1, vhiv, acc11);                                     \
      }                                                                       \
      __builtin_amdgcn_s_setprio(0);                                          \
    }                                                                         \
  } while (0)

#pragma unroll 1
  for (int kt2 = 0; kt2 < 16; ++kt2) {
    const int kt = kt2 * 2;
    STAGE(KsB, VsB, (kt + 1) * 64);
    TILE(KsA, VsA);
    __syncthreads();
    if (kt2 < 15) STAGE(KsA, VsA, (kt + 2) * 64);
    TILE(KsB, VsB);
    __syncthreads();
  }
#undef TILE
#undef STAGE

  l0 += __shfl_xor(l0, 32);
  l1 += __shfl_xor(l1, 32);
  float inv0 = 1.f / l0, inv1 = 1.f / l1;

  const int b_ = bh >> 4, h = bh & 15;
  const int qw = q0 + wave * 64;
#pragma unroll
  for (int r = 0; r < 16; ++r) {
    const int ql = (r & 3) + 8 * (r >> 2) + 4 * hi;
    float iv0 = __shfl(inv0, ql);
    float iv1 = __shfl(inv1, ql);
    size_t base0 = ((size_t)b_ * 2048 + qw + ql) * 1024 + h * 64;
    size_t base1 = base0 + (size_t)32 * 1024;
    Ob[base0 + l31] = f2bf(acc00[r] * iv0);
    Ob[base0 + 32 + l31] = f2bf(acc01[r] * iv0);
    Ob[base1 + l31] = f2bf(acc10[r] * iv1);
    Ob[base1 + 32 + l31] = f2bf(acc11[r] * iv1);
  }
}

// ---------------- launch ----------------

extern "C" void kernel_launch(void* const* d_in, const int* in_sizes, int n_in,
                              void* d_out, int out_size, void* d_ws, size_t ws_size,
                              hipStream_t stream) {
  const float* x      = (const float*)d_in[0];
  const float* w_qkv  = (const float*)d_in[1];
  const float* b_qkv  = (const float*)d_in[2];
  const float* w_proj = (const float*)d_in[3];
  const float* b_proj = (const float*)d_in[4];
  float* out = (float*)d_out;
  char* ws = (char*)d_ws;

  // workspace layout (bytes)
  u16* xb    = (u16*)(ws);                 // 16 MB  [8192][1024]; later reused as attn_out
  u16* wqkvt = (u16*)(ws + 16777216);      //  6 MB  [3072][1024]
  u16* wprjt = (u16*)(ws + 23068672);      //  2 MB  [1024][1024]
  u16* Qb    = (u16*)(ws + 25165824);      // 16 MB  [64][2048][64]
  u16* Kb    = (u16*)(ws + 41943040);      // 16 MB
  u16* Vt    = (u16*)(ws + 58720256);      // 16 MB  [64][64][2048]  (direct from gemm_qkv)
  u16* Ob    = xb;                         // alias: x consumed by gemm_qkv before attn writes
  if (ws_size < 92274688u) return;  // insufficient scratch -> visible failure

  cvt_f32_bf16<<<8192, 256, 0, stream>>>(x, xb, 8388608);
  transpose_cvt2<<<dim3(64, 16), 256, 0, stream>>>(w_qkv, w_proj, wqkvt, wprjt);
  gemm_qkv<<<dim3(64, 12), 512, 0, stream>>>(xb, wqkvt, b_qkv, Qb, Kb, Vt);
  attn_kernel<<<dim3(64, 8), 256, 0, stream>>>(Qb, Kb, Vt, Ob);
  gemm_proj<<<dim3(64, 4), 512, 0, stream>>>(Ob, wprjt, b_proj, out);
}